// Round 1
// baseline (703.496 us; speedup 1.0000x reference)
//
#include <hip/hip_runtime.h>

// batch=8, seq=16384, d=256, hidden=32, 14 levels, 10 transforms, all f32.
//
// Mean-pyramid formulation (unchanged math):
//   A_0[r]     = 0.5*(Z[2r] + Z[2r+1])
//   At_l       = MLP_t(A_l)            (stored in pyramid, overwrites A_l)
//   A_{l+1}[g] = 0.5*((A_l+At_l)[2g] + (A_l+At_l)[2g+1])
//   out[b,s]   = Z[b,s] + sum_l At_l[b, s>>(l+1)]
// Pyramid: level l row-offset = 131072-(131072>>l); 131064 rows total.
//
// This version: k_fused does A_0 staging + levels 0..4 per block entirely in
// LDS (no weight staging -> 39 KB LDS -> ~3 blocks/CU instead of 1);
// k_tail walks levels 5..13 (2 MB, L2-resident) with block-local level sync.

__device__ __forceinline__ float gelu_t(float x){
  float t = tanhf(0.7978845608028654f * (x + 0.044715f * x * x * x));
  return 0.5f * x * (1.0f + t);
}

#define SA 260   // LDS row stride (f32): 16B-aligned, 4-bank skew per row

// ---------- kernel 1: fused A0 + levels 0..4 ----------
// block = 32 A_0 rows (64 Z rows). Writes At_0..At_4 and one A_5 row.
__global__ void __launch_bounds__(256) k_fused(
    const float* __restrict__ Z, float* __restrict__ P,
    const float* __restrict__ W1, const float* __restrict__ B1,
    const float* __restrict__ W2, const float* __restrict__ B2)
{
  __shared__ __align__(16) float a_s[32 * SA];   // 33.3 KB
  __shared__ float h_s[32 * 33];                 //  4.2 KB
  const int tid = threadIdx.x;
  const long arow0 = (long)blockIdx.x * 32;      // first A_0 row of this block

  // stage A_0 = 0.5*(Z[2r] + Z[2r+1]) for 32 rows
  {
    const float* Zb = Z + (arow0 << 9);          // 2*arow0 rows * 256
    for(int c = tid; c < 2048; c += 256){
      int r = c >> 6, q = (c & 63) << 2;
      float4 x = *(const float4*)(Zb + ((long)r << 9) + q);
      float4 y = *(const float4*)(Zb + ((long)r << 9) + 256 + q);
      float4 o;
      o.x = 0.5f*(x.x + y.x); o.y = 0.5f*(x.y + y.y);
      o.z = 0.5f*(x.z + y.z); o.w = 0.5f*(x.w + y.w);
      *(float4*)&a_s[r * SA + q] = o;
    }
  }
  __syncthreads();

  int nr = 32;
  for(int l = 0; l < 5; l++){                    // t = min(l,9) = l here
    const float* W1g = W1 + ((long)l << 13);
    const float* B1g = B1 + (l << 5);
    const float* W2g = W2 + ((long)l << 13);
    const float* B2g = B2 + (l << 8);
    const long Prow = (long)(131072 - (131072 >> l)) + (arow0 >> l);

    // h[r][j] = gelu(A[r]·W1[:,j] + b1[j]); task = (row, 4 consecutive j)
    // W1 read in natural [d][32] layout from global (L1/L2 broadcast).
    for(int task = tid; task < (nr << 3); task += 256){
      int r = task >> 3, j4 = (task & 7) << 2;
      float4 acc = *(const float4*)(B1g + j4);
      const float4* ap = (const float4*)&a_s[r * SA];
      #pragma unroll 4
      for(int d4 = 0; d4 < 64; d4++){
        float4 a = ap[d4];
        const float* wr = W1g + (d4 << 7) + j4;  // rows 4*d4..4*d4+3
        float4 w0 = *(const float4*)(wr);
        float4 w1 = *(const float4*)(wr + 32);
        float4 w2 = *(const float4*)(wr + 64);
        float4 w3 = *(const float4*)(wr + 96);
        acc.x += a.x*w0.x + a.y*w1.x + a.z*w2.x + a.w*w3.x;
        acc.y += a.x*w0.y + a.y*w1.y + a.z*w2.y + a.w*w3.y;
        acc.z += a.x*w0.z + a.y*w1.z + a.z*w2.z + a.w*w3.z;
        acc.w += a.x*w0.w + a.y*w1.w + a.z*w2.w + a.w*w3.w;
      }
      int hb = r * 33 + j4;
      h_s[hb+0] = gelu_t(acc.x); h_s[hb+1] = gelu_t(acc.y);
      h_s[hb+2] = gelu_t(acc.z); h_s[hb+3] = gelu_t(acc.w);
    }
    __syncthreads();

    // At rows -> P; pair means held in registers across the barrier, then
    // written back into a_s (avoids RAW hazard without a second tile).
    const int ntask = nr << 4;                   // (nr/2)*32, max 512
    float m0[8], m1[8];
    for(int task = tid, it = 0; task < ntask; task += 256, it++){
      int rp = task >> 5, d8 = (task & 31) << 3;
      int r0 = rp << 1, r1 = r0 | 1;
      float acc0[8], acc1[8];
      #pragma unroll
      for(int k = 0; k < 8; k++){ float bb = B2g[d8 + k]; acc0[k] = bb; acc1[k] = bb; }
      #pragma unroll 4
      for(int j = 0; j < 32; j++){
        float h0 = h_s[r0*33 + j], h1 = h_s[r1*33 + j];
        const float* wr = W2g + (j << 8) + d8;
        float4 wa = *(const float4*)(wr);
        float4 wb = *(const float4*)(wr + 4);
        acc0[0] += h0*wa.x; acc0[1] += h0*wa.y; acc0[2] += h0*wa.z; acc0[3] += h0*wa.w;
        acc0[4] += h0*wb.x; acc0[5] += h0*wb.y; acc0[6] += h0*wb.z; acc0[7] += h0*wb.w;
        acc1[0] += h1*wa.x; acc1[1] += h1*wa.y; acc1[2] += h1*wa.z; acc1[3] += h1*wa.w;
        acc1[4] += h1*wb.x; acc1[5] += h1*wb.y; acc1[6] += h1*wb.z; acc1[7] += h1*wb.w;
      }
      float* at0 = P + ((Prow + r0) << 8) + d8;
      float* at1 = P + ((Prow + r1) << 8) + d8;
      *(float4*)(at0)     = make_float4(acc0[0], acc0[1], acc0[2], acc0[3]);
      *(float4*)(at0 + 4) = make_float4(acc0[4], acc0[5], acc0[6], acc0[7]);
      *(float4*)(at1)     = make_float4(acc1[0], acc1[1], acc1[2], acc1[3]);
      *(float4*)(at1 + 4) = make_float4(acc1[4], acc1[5], acc1[6], acc1[7]);
      float4 A0a = *(const float4*)&a_s[r0*SA + d8];
      float4 A0b = *(const float4*)&a_s[r0*SA + d8 + 4];
      float4 A1a = *(const float4*)&a_s[r1*SA + d8];
      float4 A1b = *(const float4*)&a_s[r1*SA + d8 + 4];
      float* mm = it ? m1 : m0;
      mm[0] = 0.5f*(A0a.x + acc0[0] + A1a.x + acc1[0]);
      mm[1] = 0.5f*(A0a.y + acc0[1] + A1a.y + acc1[1]);
      mm[2] = 0.5f*(A0a.z + acc0[2] + A1a.z + acc1[2]);
      mm[3] = 0.5f*(A0a.w + acc0[3] + A1a.w + acc1[3]);
      mm[4] = 0.5f*(A0b.x + acc0[4] + A1b.x + acc1[4]);
      mm[5] = 0.5f*(A0b.y + acc0[5] + A1b.y + acc1[5]);
      mm[6] = 0.5f*(A0b.z + acc0[6] + A1b.z + acc1[6]);
      mm[7] = 0.5f*(A0b.w + acc0[7] + A1b.w + acc1[7]);
    }
    __syncthreads();

    if(l < 4){
      for(int task = tid, it = 0; task < ntask; task += 256, it++){
        int rp = task >> 5, d8 = (task & 31) << 3;
        float* mm = it ? m1 : m0;
        *(float4*)&a_s[rp*SA + d8]     = make_float4(mm[0], mm[1], mm[2], mm[3]);
        *(float4*)&a_s[rp*SA + d8 + 4] = make_float4(mm[4], mm[5], mm[6], mm[7]);
      }
      __syncthreads();
    } else if(tid < 32){
      // l == 4: single pair -> one A_5 row at global row 126976 + blockIdx.x
      long p5 = (((long)126976 + blockIdx.x) << 8) + (tid << 3);
      *(float4*)(P + p5)     = make_float4(m0[0], m0[1], m0[2], m0[3]);
      *(float4*)(P + p5 + 4) = make_float4(m0[4], m0[5], m0[6], m0[7]);
    }
    nr >>= 1;
  }
}

// ---------- kernel 2: tail levels [l0..l1], block-local sync per level ----------
// grid = 8 << ss blocks; block handles batch b = blockIdx>>ss, subtree sub.
// Valid while rows-per-sub >= 2 at every level < l1 (ss=1 ok through l=11).
__global__ void __launch_bounds__(512) k_tail(
    float* __restrict__ P,
    const float* __restrict__ W1, const float* __restrict__ B1,
    const float* __restrict__ W2, const float* __restrict__ B2,
    int l0, int l1, int ss)
{
  __shared__ float h_s[128 * 33];                // max nbs = 128 (l=5, ss=1)
  const int tid = threadIdx.x;
  const int b   = blockIdx.x >> ss;
  const int sub = blockIdx.x & ((1 << ss) - 1);

  for(int l = l0; l <= l1; l++){
    int t = (l < 9) ? l : 9;
    const float* W1g = W1 + ((long)t << 13);
    const float* B1g = B1 + (t << 5);
    const float* W2g = W2 + ((long)t << 13);
    const float* B2g = B2 + (t << 8);
    int nbb = 8192 >> l;                          // rows per batch
    int nbs = nbb >> ss;                          // rows per sub-block
    long rowA = (long)(131072 - (131072 >> l)) + (long)b * nbb + (long)sub * nbs;
    float* A = P + (rowA << 8);

    for(int task = tid; task < (nbs << 3); task += 512){
      int r = task >> 3, j4 = (task & 7) << 2;
      float4 acc = *(const float4*)(B1g + j4);
      const float4* ap = (const float4*)(A + ((long)r << 8));
      #pragma unroll 4
      for(int d4 = 0; d4 < 64; d4++){
        float4 a = ap[d4];
        const float* wr = W1g + (d4 << 7) + j4;
        float4 w0 = *(const float4*)(wr);
        float4 w1 = *(const float4*)(wr + 32);
        float4 w2 = *(const float4*)(wr + 64);
        float4 w3 = *(const float4*)(wr + 96);
        acc.x += a.x*w0.x + a.y*w1.x + a.z*w2.x + a.w*w3.x;
        acc.y += a.x*w0.y + a.y*w1.y + a.z*w2.y + a.w*w3.y;
        acc.z += a.x*w0.z + a.y*w1.z + a.z*w2.z + a.w*w3.z;
        acc.w += a.x*w0.w + a.y*w1.w + a.z*w2.w + a.w*w3.w;
      }
      int hb = r * 33 + j4;
      h_s[hb+0] = gelu_t(acc.x); h_s[hb+1] = gelu_t(acc.y);
      h_s[hb+2] = gelu_t(acc.z); h_s[hb+3] = gelu_t(acc.w);
    }
    __syncthreads();

    int pairs = nbs >> 1;
    if(pairs){
      long rowN = (long)(131072 - (131072 >> (l+1))) + (long)b * (nbb >> 1) + (long)sub * pairs;
      float* An = P + (rowN << 8);
      for(int task = tid; task < (pairs << 5); task += 512){
        int rp = task >> 5, d8 = (task & 31) << 3;
        int r0 = rp << 1, r1 = r0 | 1;
        float* a0 = A + ((long)r0 << 8) + d8;
        float* a1 = A + ((long)r1 << 8) + d8;
        float4 o0a = *(const float4*)(a0), o0b = *(const float4*)(a0 + 4);
        float4 o1a = *(const float4*)(a1), o1b = *(const float4*)(a1 + 4);
        float acc0[8], acc1[8];
        #pragma unroll
        for(int k = 0; k < 8; k++){ float bb = B2g[d8 + k]; acc0[k] = bb; acc1[k] = bb; }
        #pragma unroll 4
        for(int j = 0; j < 32; j++){
          float h0 = h_s[r0*33 + j], h1 = h_s[r1*33 + j];
          const float* wr = W2g + (j << 8) + d8;
          float4 wa = *(const float4*)(wr);
          float4 wb = *(const float4*)(wr + 4);
          acc0[0] += h0*wa.x; acc0[1] += h0*wa.y; acc0[2] += h0*wa.z; acc0[3] += h0*wa.w;
          acc0[4] += h0*wb.x; acc0[5] += h0*wb.y; acc0[6] += h0*wb.z; acc0[7] += h0*wb.w;
          acc1[0] += h1*wa.x; acc1[1] += h1*wa.y; acc1[2] += h1*wa.z; acc1[3] += h1*wa.w;
          acc1[4] += h1*wb.x; acc1[5] += h1*wb.y; acc1[6] += h1*wb.z; acc1[7] += h1*wb.w;
        }
        // write At in place (this thread owns exactly these elements)
        *(float4*)(a0)     = make_float4(acc0[0], acc0[1], acc0[2], acc0[3]);
        *(float4*)(a0 + 4) = make_float4(acc0[4], acc0[5], acc0[6], acc0[7]);
        *(float4*)(a1)     = make_float4(acc1[0], acc1[1], acc1[2], acc1[3]);
        *(float4*)(a1 + 4) = make_float4(acc1[4], acc1[5], acc1[6], acc1[7]);
        float4 ma, mb;
        ma.x = 0.5f*(o0a.x + acc0[0] + o1a.x + acc1[0]);
        ma.y = 0.5f*(o0a.y + acc0[1] + o1a.y + acc1[1]);
        ma.z = 0.5f*(o0a.z + acc0[2] + o1a.z + acc1[2]);
        ma.w = 0.5f*(o0a.w + acc0[3] + o1a.w + acc1[3]);
        mb.x = 0.5f*(o0b.x + acc0[4] + o1b.x + acc1[4]);
        mb.y = 0.5f*(o0b.y + acc0[5] + o1b.y + acc1[5]);
        mb.z = 0.5f*(o0b.z + acc0[6] + o1b.z + acc1[6]);
        mb.w = 0.5f*(o0b.w + acc0[7] + o1b.w + acc1[7]);
        *(float4*)(An + ((long)rp << 8) + d8)     = ma;
        *(float4*)(An + ((long)rp << 8) + d8 + 4) = mb;
      }
    } else if(tid < 32){
      // single row (l == 13): in-place At, no next level
      int d8 = tid << 3;
      float acc0[8];
      #pragma unroll
      for(int k = 0; k < 8; k++) acc0[k] = B2g[d8 + k];
      #pragma unroll 4
      for(int j = 0; j < 32; j++){
        float h0 = h_s[j];
        const float* wr = W2g + (j << 8) + d8;
        float4 wa = *(const float4*)(wr);
        float4 wb = *(const float4*)(wr + 4);
        acc0[0] += h0*wa.x; acc0[1] += h0*wa.y; acc0[2] += h0*wa.z; acc0[3] += h0*wa.w;
        acc0[4] += h0*wb.x; acc0[5] += h0*wb.y; acc0[6] += h0*wb.z; acc0[7] += h0*wb.w;
      }
      *(float4*)(A + d8)     = make_float4(acc0[0], acc0[1], acc0[2], acc0[3]);
      *(float4*)(A + d8 + 4) = make_float4(acc0[4], acc0[5], acc0[6], acc0[7]);
    }
    __syncthreads();   // block-scope visibility of global writes before next level
  }
}

// ---------- kernel 3: out[b,s] = Z[b,s] + sum_l At_l[b, s>>(l+1)] ----------
__global__ void __launch_bounds__(256) k_final(const float* __restrict__ Z,
                                               const float* __restrict__ P,
                                               float* __restrict__ out){
  long t = (long)blockIdx.x * 256 + threadIdx.x;
  long base = t * 4;
  long row  = base >> 8;
  int  doff = (int)(base & 255);
  int  b = (int)(row >> 14), s = (int)(row & 16383);
  float4 acc = *(const float4*)(Z + base);
  #pragma unroll
  for(int l = 0; l < 14; l++){
    int rowoff = 131072 - (131072 >> l);
    int g = s >> (l + 1);
    long p = ((long)(rowoff + (b << (13 - l)) + g) << 8) + doff;
    float4 f = *(const float4*)(P + p);
    acc.x += f.x; acc.y += f.y; acc.z += f.z; acc.w += f.w;
  }
  *(float4*)(out + base) = acc;
}

extern "C" void kernel_launch(void* const* d_in, const int* in_sizes, int n_in,
                              void* d_out, int out_size, void* d_ws, size_t ws_size,
                              hipStream_t stream) {
  const float* Z  = (const float*)d_in[0];
  const float* W1 = (const float*)d_in[1];
  const float* B1 = (const float*)d_in[2];
  const float* W2 = (const float*)d_in[3];
  const float* B2 = (const float*)d_in[4];

  const size_t pyr_elems = 33552384;              // 131064 rows * 256
  const bool   use_ws    = ws_size >= pyr_elems * sizeof(float);
  float* P = use_ws ? (float*)d_ws : (float*)d_out;

  // levels 0..4 fused with A_0 staging (replaces k_mean0 + 5 k_mlp launches)
  k_fused<<<2048, 256, 0, stream>>>(Z, P, W1, B1, W2, B2);
  // levels 5..11 (2 subtrees per batch), then 12..13 (1 per batch)
  k_tail<<<16, 512, 0, stream>>>(P, W1, B1, W2, B2, 5, 11, 1);
  k_tail<<<8,  512, 0, stream>>>(P, W1, B1, W2, B2, 12, 13, 0);

  if(use_ws){
    k_final<<<32768, 256, 0, stream>>>(Z, P, (float*)d_out);
  }else{
    // pyramid occupies d_out: accumulate into Z's buffer (harness restores
    // inputs before every launch), then D2D copy
    k_final<<<32768, 256, 0, stream>>>(Z, P, (float*)d_in[0]);
    hipMemcpyAsync(d_out, d_in[0], (size_t)out_size * sizeof(float),
                   hipMemcpyDeviceToDevice, stream);
  }
}

// Round 2
// 598.238 us; speedup vs baseline: 1.1759x; 1.1759x over previous
//
#include <hip/hip_runtime.h>

// batch=8, seq=16384, d=256, hidden=32, 14 levels, 10 transforms, all f32.
//
// Mean-pyramid formulation (unchanged math):
//   A_0[r]     = 0.5*(Z[2r] + Z[2r+1])
//   At_l       = MLP_t(A_l)            (stored in pyramid, overwrites A_l)
//   A_{l+1}[g] = 0.5*((A_l+At_l)[2g] + (A_l+At_l)[2g+1])
//   out[b,s]   = Z[b,s] + sum_l At_l[b, s>>(l+1)]
// Pyramid: level l row-offset = 131072-(131072>>l); 131064 rows total.
//
// v2: weights staged in LDS *compactly* (no padding; layouts chosen so the
// access patterns are broadcast/contiguous => conflict-free), W1/W2 share one
// 32KB union buffer (h-phase then At-phase). LDS ~71.6KB -> 2 blocks/CU,
// all GEMM operands LDS-fed (v1's global weight loads were latency-bound).

__device__ __forceinline__ float gelu_t(float x){
  float t = tanhf(0.7978845608028654f * (x + 0.044715f * x * x * x));
  return 0.5f * x * (1.0f + t);
}

#define SA 260   // a_s row stride (f32): 16B-aligned, 4-bank skew per row

// ---------- kernel 1: fused A0 + levels 0..4 ----------
// block = 32 A_0 rows (64 Z rows). Writes At_0..At_4 and one A_5 row.
__global__ void __launch_bounds__(256) k_fused(
    const float* __restrict__ Z, float* __restrict__ P,
    const float* __restrict__ W1, const float* __restrict__ B1,
    const float* __restrict__ W2, const float* __restrict__ B2)
{
  __shared__ __align__(16) float a_s[32 * SA];   // 33.3 KB
  __shared__ __align__(16) float w_s[8192];      // 32 KB: W1 [256][32] then W2 [32][256]
  __shared__ __align__(16) float h_s[32 * 34];   //  4.3 KB, TRANSPOSED: h_s[j*34 + r]
  __shared__ __align__(16) float b1s[32];
  __shared__ __align__(16) float b2s[256];
  const int tid = threadIdx.x;
  const long arow0 = (long)blockIdx.x * 32;

  // stage A_0 = 0.5*(Z[2r] + Z[2r+1]) for 32 rows (barrier comes inside loop)
  {
    const float* Zb = Z + (arow0 << 9);
    for(int c = tid; c < 2048; c += 256){
      int r = c >> 6, q = (c & 63) << 2;
      float4 x = *(const float4*)(Zb + ((long)r << 9) + q);
      float4 y = *(const float4*)(Zb + ((long)r << 9) + 256 + q);
      float4 o;
      o.x = 0.5f*(x.x + y.x); o.y = 0.5f*(x.y + y.y);
      o.z = 0.5f*(x.z + y.z); o.w = 0.5f*(x.w + y.w);
      *(float4*)&a_s[r * SA + q] = o;
    }
  }

  int nr = 32;
  for(int l = 0; l < 5; l++){                    // t = min(l,9) = l here
    const float* W1g = W1 + ((long)l << 13);
    const float* B1g = B1 + (l << 5);
    const float* W2g = W2 + ((long)l << 13);
    const float* B2g = B2 + (l << 8);
    const long Prow = (long)(131072 - (131072 >> l)) + (arow0 >> l);

    // stage W1 (natural [d][j] layout, compact) + biases
    for(int c = tid; c < 2048; c += 256)
      *(float4*)&w_s[c << 2] = *(const float4*)(W1g + (c << 2));
    if(tid < 32) b1s[tid] = B1g[tid];
    b2s[tid] = B2g[tid];
    __syncthreads();   // covers a_s staging (l==0) / mean write-back (l>0) too

    // h-phase: task=(r, j4). W1 read is 128B-contiguous per 8 lanes +
    // broadcast across row-groups; a_s read is 8 distinct skewed rows.
    for(int task = tid; task < (nr << 3); task += 256){
      int r = task >> 3, j4 = (task & 7) << 2;
      float4 acc = *(const float4*)&b1s[j4];
      const float4* ap = (const float4*)&a_s[r * SA];
      #pragma unroll 4
      for(int d4 = 0; d4 < 64; d4++){
        float4 a = ap[d4];
        const float* wb = &w_s[(d4 << 7) + j4];   // rows 4*d4 .. 4*d4+3
        float4 w0 = *(const float4*)(wb);
        float4 w1 = *(const float4*)(wb + 32);
        float4 w2 = *(const float4*)(wb + 64);
        float4 w3 = *(const float4*)(wb + 96);
        acc.x += a.x*w0.x + a.y*w1.x + a.z*w2.x + a.w*w3.x;
        acc.y += a.x*w0.y + a.y*w1.y + a.z*w2.y + a.w*w3.y;
        acc.z += a.x*w0.z + a.y*w1.z + a.z*w2.z + a.w*w3.z;
        acc.w += a.x*w0.w + a.y*w1.w + a.z*w2.w + a.w*w3.w;
      }
      h_s[(j4+0)*34 + r] = gelu_t(acc.x);
      h_s[(j4+1)*34 + r] = gelu_t(acc.y);
      h_s[(j4+2)*34 + r] = gelu_t(acc.z);
      h_s[(j4+3)*34 + r] = gelu_t(acc.w);
    }
    __syncthreads();

    // overwrite w_s with W2 ([j][d] natural, compact)
    for(int c = tid; c < 2048; c += 256)
      *(float4*)&w_s[c << 2] = *(const float4*)(W2g + (c << 2));
    __syncthreads();

    // At-phase: task=(rp, d4): float4 of both rows of a pair.
    // w_s row read is a contiguous 1KB wave read; h read is broadcast float2.
    const int npair = nr >> 1;
    const int ntask = npair << 6;
    float4 m[4];
    #pragma unroll
    for(int it = 0; it < 4; it++){
      int task = tid + (it << 8);
      if(task < ntask){
        int rp = task >> 6, d4 = (task & 63) << 2;
        int r0 = rp << 1;
        float4 acc0 = *(const float4*)&b2s[d4];
        float4 acc1 = acc0;
        #pragma unroll 4
        for(int j = 0; j < 32; j++){
          float2 hh = *(const float2*)&h_s[j*34 + r0];
          float4 w  = *(const float4*)&w_s[(j << 8) + d4];
          acc0.x += hh.x*w.x; acc0.y += hh.x*w.y;
          acc0.z += hh.x*w.z; acc0.w += hh.x*w.w;
          acc1.x += hh.y*w.x; acc1.y += hh.y*w.y;
          acc1.z += hh.y*w.z; acc1.w += hh.y*w.w;
        }
        *(float4*)(P + ((Prow + r0)     << 8) + d4) = acc0;
        *(float4*)(P + ((Prow + r0 + 1) << 8) + d4) = acc1;
        float4 A0 = *(const float4*)&a_s[ r0    * SA + d4];
        float4 A1 = *(const float4*)&a_s[(r0+1) * SA + d4];
        m[it].x = 0.5f*(A0.x + acc0.x + A1.x + acc1.x);
        m[it].y = 0.5f*(A0.y + acc0.y + A1.y + acc1.y);
        m[it].z = 0.5f*(A0.z + acc0.z + A1.z + acc1.z);
        m[it].w = 0.5f*(A0.w + acc0.w + A1.w + acc1.w);
      }
    }
    __syncthreads();

    if(l < 4){
      #pragma unroll
      for(int it = 0; it < 4; it++){
        int task = tid + (it << 8);
        if(task < ntask){
          int rp = task >> 6, d4 = (task & 63) << 2;
          *(float4*)&a_s[rp * SA + d4] = m[it];
        }
      }
      // next level's post-stage barrier orders these writes before reads
    } else if(tid < 64){
      // l == 4: single pair -> one A_5 row at global row 126976 + blockIdx.x
      long p5 = (((long)126976 + blockIdx.x) << 8) + (tid << 2);
      *(float4*)(P + p5) = m[0];
    }
    nr >>= 1;
  }
}

// ---------- kernel 2: tail levels [l0..l1], block-local sync per level ----------
// grid = 8 << ss blocks; block handles batch b = blockIdx>>ss, subtree sub.
__global__ void __launch_bounds__(512) k_tail(
    float* __restrict__ P,
    const float* __restrict__ W1, const float* __restrict__ B1,
    const float* __restrict__ W2, const float* __restrict__ B2,
    int l0, int l1, int ss)
{
  __shared__ float h_s[128 * 33];                // max nbs = 128 (l=5, ss=1)
  __shared__ __align__(16) float w1s[8192];      // 32 KB, natural [d][j]
  __shared__ __align__(16) float w2s[8192];      // 32 KB, natural [j][d]
  const int tid = threadIdx.x;
  const int b   = blockIdx.x >> ss;
  const int sub = blockIdx.x & ((1 << ss) - 1);

  for(int l = l0; l <= l1; l++){
    int t = (l < 9) ? l : 9;
    const float* W1g = W1 + ((long)t << 13);
    const float* B1g = B1 + (t << 5);
    const float* W2g = W2 + ((long)t << 13);
    const float* B2g = B2 + (t << 8);
    // stage weights for this level (prev level's end-barrier orders w reuse)
    for(int c = tid; c < 2048; c += 512){
      *(float4*)&w1s[c << 2] = *(const float4*)(W1g + (c << 2));
      *(float4*)&w2s[c << 2] = *(const float4*)(W2g + (c << 2));
    }
    __syncthreads();

    int nbb = 8192 >> l;                          // rows per batch
    int nbs = nbb >> ss;                          // rows per sub-block
    long rowA = (long)(131072 - (131072 >> l)) + (long)b * nbb + (long)sub * nbs;
    float* A = P + (rowA << 8);

    for(int task = tid; task < (nbs << 3); task += 512){
      int r = task >> 3, j4 = (task & 7) << 2;
      float4 acc = *(const float4*)(B1g + j4);
      const float4* ap = (const float4*)(A + ((long)r << 8));
      #pragma unroll 4
      for(int d4 = 0; d4 < 64; d4++){
        float4 a = ap[d4];
        const float* wr = &w1s[(d4 << 7) + j4];
        float4 w0 = *(const float4*)(wr);
        float4 w1 = *(const float4*)(wr + 32);
        float4 w2 = *(const float4*)(wr + 64);
        float4 w3 = *(const float4*)(wr + 96);
        acc.x += a.x*w0.x + a.y*w1.x + a.z*w2.x + a.w*w3.x;
        acc.y += a.x*w0.y + a.y*w1.y + a.z*w2.y + a.w*w3.y;
        acc.z += a.x*w0.z + a.y*w1.z + a.z*w2.z + a.w*w3.z;
        acc.w += a.x*w0.w + a.y*w1.w + a.z*w2.w + a.w*w3.w;
      }
      int hb = r * 33 + j4;
      h_s[hb+0] = gelu_t(acc.x); h_s[hb+1] = gelu_t(acc.y);
      h_s[hb+2] = gelu_t(acc.z); h_s[hb+3] = gelu_t(acc.w);
    }
    __syncthreads();

    int pairs = nbs >> 1;
    if(pairs){
      long rowN = (long)(131072 - (131072 >> (l+1))) + (long)b * (nbb >> 1) + (long)sub * pairs;
      float* An = P + (rowN << 8);
      for(int task = tid; task < (pairs << 5); task += 512){
        int rp = task >> 5, d8 = (task & 31) << 3;
        int r0 = rp << 1, r1 = r0 | 1;
        float* a0 = A + ((long)r0 << 8) + d8;
        float* a1 = A + ((long)r1 << 8) + d8;
        float4 o0a = *(const float4*)(a0), o0b = *(const float4*)(a0 + 4);
        float4 o1a = *(const float4*)(a1), o1b = *(const float4*)(a1 + 4);
        float acc0[8], acc1[8];
        #pragma unroll
        for(int k = 0; k < 8; k++){ float bb = B2g[d8 + k]; acc0[k] = bb; acc1[k] = bb; }
        #pragma unroll 4
        for(int j = 0; j < 32; j++){
          float h0 = h_s[r0*33 + j], h1 = h_s[r1*33 + j];
          const float* wr = &w2s[(j << 8) + d8];
          float4 wa = *(const float4*)(wr);
          float4 wb = *(const float4*)(wr + 4);
          acc0[0] += h0*wa.x; acc0[1] += h0*wa.y; acc0[2] += h0*wa.z; acc0[3] += h0*wa.w;
          acc0[4] += h0*wb.x; acc0[5] += h0*wb.y; acc0[6] += h0*wb.z; acc0[7] += h0*wb.w;
          acc1[0] += h1*wa.x; acc1[1] += h1*wa.y; acc1[2] += h1*wa.z; acc1[3] += h1*wa.w;
          acc1[4] += h1*wb.x; acc1[5] += h1*wb.y; acc1[6] += h1*wb.z; acc1[7] += h1*wb.w;
        }
        *(float4*)(a0)     = make_float4(acc0[0], acc0[1], acc0[2], acc0[3]);
        *(float4*)(a0 + 4) = make_float4(acc0[4], acc0[5], acc0[6], acc0[7]);
        *(float4*)(a1)     = make_float4(acc1[0], acc1[1], acc1[2], acc1[3]);
        *(float4*)(a1 + 4) = make_float4(acc1[4], acc1[5], acc1[6], acc1[7]);
        float4 ma, mb;
        ma.x = 0.5f*(o0a.x + acc0[0] + o1a.x + acc1[0]);
        ma.y = 0.5f*(o0a.y + acc0[1] + o1a.y + acc1[1]);
        ma.z = 0.5f*(o0a.z + acc0[2] + o1a.z + acc1[2]);
        ma.w = 0.5f*(o0a.w + acc0[3] + o1a.w + acc1[3]);
        mb.x = 0.5f*(o0b.x + acc0[4] + o1b.x + acc1[4]);
        mb.y = 0.5f*(o0b.y + acc0[5] + o1b.y + acc1[5]);
        mb.z = 0.5f*(o0b.z + acc0[6] + o1b.z + acc1[6]);
        mb.w = 0.5f*(o0b.w + acc0[7] + o1b.w + acc1[7]);
        *(float4*)(An + ((long)rp << 8) + d8)     = ma;
        *(float4*)(An + ((long)rp << 8) + d8 + 4) = mb;
      }
    } else if(tid < 32){
      // single row (l == 13): in-place At, no next level
      int d8 = tid << 3;
      float acc0[8];
      #pragma unroll
      for(int k = 0; k < 8; k++) acc0[k] = B2g[d8 + k];
      #pragma unroll 4
      for(int j = 0; j < 32; j++){
        float h0 = h_s[j];
        const float* wr = &w2s[(j << 8) + d8];
        float4 wa = *(const float4*)(wr);
        float4 wb = *(const float4*)(wr + 4);
        acc0[0] += h0*wa.x; acc0[1] += h0*wa.y; acc0[2] += h0*wa.z; acc0[3] += h0*wa.w;
        acc0[4] += h0*wb.x; acc0[5] += h0*wb.y; acc0[6] += h0*wb.z; acc0[7] += h0*wb.w;
      }
      *(float4*)(A + d8)     = make_float4(acc0[0], acc0[1], acc0[2], acc0[3]);
      *(float4*)(A + d8 + 4) = make_float4(acc0[4], acc0[5], acc0[6], acc0[7]);
    }
    __syncthreads();   // block-scope visibility of global writes before next level
  }
}

// ---------- kernel 3: out[b,s] = Z[b,s] + sum_l At_l[b, s>>(l+1)] ----------
__global__ void __launch_bounds__(256) k_final(const float* __restrict__ Z,
                                               const float* __restrict__ P,
                                               float* __restrict__ out){
  long t = (long)blockIdx.x * 256 + threadIdx.x;
  long base = t * 4;
  long row  = base >> 8;
  int  doff = (int)(base & 255);
  int  b = (int)(row >> 14), s = (int)(row & 16383);
  float4 acc = *(const float4*)(Z + base);
  #pragma unroll
  for(int l = 0; l < 14; l++){
    int rowoff = 131072 - (131072 >> l);
    int g = s >> (l + 1);
    long p = ((long)(rowoff + (b << (13 - l)) + g) << 8) + doff;
    float4 f = *(const float4*)(P + p);
    acc.x += f.x; acc.y += f.y; acc.z += f.z; acc.w += f.w;
  }
  *(float4*)(out + base) = acc;
}

extern "C" void kernel_launch(void* const* d_in, const int* in_sizes, int n_in,
                              void* d_out, int out_size, void* d_ws, size_t ws_size,
                              hipStream_t stream) {
  const float* Z  = (const float*)d_in[0];
  const float* W1 = (const float*)d_in[1];
  const float* B1 = (const float*)d_in[2];
  const float* W2 = (const float*)d_in[3];
  const float* B2 = (const float*)d_in[4];

  const size_t pyr_elems = 33552384;              // 131064 rows * 256
  const bool   use_ws    = ws_size >= pyr_elems * sizeof(float);
  float* P = use_ws ? (float*)d_ws : (float*)d_out;

  // levels 0..4 fused with A_0 staging
  k_fused<<<2048, 256, 0, stream>>>(Z, P, W1, B1, W2, B2);
  // levels 5..11 (2 subtrees per batch), then 12..13 (1 per batch)
  k_tail<<<16, 512, 0, stream>>>(P, W1, B1, W2, B2, 5, 11, 1);
  k_tail<<<8,  512, 0, stream>>>(P, W1, B1, W2, B2, 12, 13, 0);

  if(use_ws){
    k_final<<<32768, 256, 0, stream>>>(Z, P, (float*)d_out);
  }else{
    // pyramid occupies d_out: accumulate into Z's buffer (harness restores
    // inputs before every launch), then D2D copy
    k_final<<<32768, 256, 0, stream>>>(Z, P, (float*)d_in[0]);
    hipMemcpyAsync(d_out, d_in[0], (size_t)out_size * sizeof(float),
                   hipMemcpyDeviceToDevice, stream);
  }
}